// Round 6
// baseline (283.669 us; speedup 1.0000x reference)
//
#include <hip/hip_runtime.h>

// Attention: qkv = x @ W^T + b ; causal MHA ; B=4 T=2048 C=1024 H=16 D=64
// R6: (1) flash: subtile-split across waves — each wave owns the full 64-t
//     q-tile, processes every 4th K-subtile in a PRIVATE 16KB LDS region:
//     tile staged once / read once (was read 4x), barrier-free main loop
//     (fixed-m partials over disjoint s are additive; LDS reduction at end).
//     (2) K/V stored PRE-TILED in the flash LDS format by the GEMM epilogue:
//     staging = 16 contiguous 1KB DMAs; all ds_reads are frag_base + lane*16
//     -> conflict-free in LANE order (R5's frag-order layout 4-way conflicted).
//     (3) GEMM LDS layout lane-ordered the same way.
// Workspace (70 MB): xb@0 [8192][1024] | wb@16M [3072][1024]
//   qb@22M q bf16 [bh][t][d] *0.125*log2e
//   kvb@38M tiles [bh][st][ K: frag(ns,ks)*64+lane x8 | V: (sb*64+d)*8 ] 16KB each

typedef __attribute__((ext_vector_type(8))) short short8;
typedef __attribute__((ext_vector_type(4))) short s16x4;
typedef __attribute__((ext_vector_type(4))) float f32x4;

#define AS1 __attribute__((address_space(1)))
#define AS3 __attribute__((address_space(3)))

__device__ __forceinline__ unsigned short f2bf(float f) {
  unsigned int u = __float_as_uint(f);
  u += 0x7fffu + ((u >> 16) & 1u);
  return (unsigned short)(u >> 16);
}

__device__ __forceinline__ unsigned int pack_bf16(float lo, float hi) {
  return __builtin_amdgcn_perm(__float_as_uint(hi) + 0x8000u,
                               __float_as_uint(lo) + 0x8000u, 0x07060302u);
}

// async 16B/lane global->LDS; LDS dest = wave-uniform base + lane*16
__device__ __forceinline__ void async_copy16(const unsigned short* g, unsigned short* l) {
  const AS1 unsigned char* gp = (const AS1 unsigned char*)(unsigned long long)(uintptr_t)g;
  AS3 unsigned char* lp = (AS3 unsigned char*)(unsigned int)(uintptr_t)l;
  __builtin_amdgcn_global_load_lds((const AS1 void*)gp, (AS3 void*)lp, 16, 0, 0);
}

// ---------------- fp32 -> bf16 bulk convert ----------------
__global__ __launch_bounds__(256) void cvt_bf16(const float* __restrict__ in,
                                                unsigned short* __restrict__ out,
                                                int n8) {
  int i = blockIdx.x * 256 + threadIdx.x;
  if (i >= n8) return;
  const float4* p = (const float4*)in + (size_t)i * 2;
  float4 a = p[0], b = p[1];
  uint4 o;
  o.x = (unsigned)f2bf(a.x) | ((unsigned)f2bf(a.y) << 16);
  o.y = (unsigned)f2bf(a.z) | ((unsigned)f2bf(a.w) << 16);
  o.z = (unsigned)f2bf(b.x) | ((unsigned)f2bf(b.y) << 16);
  o.w = (unsigned)f2bf(b.z) | ((unsigned)f2bf(b.w) << 16);
  *(uint4*)(out + (size_t)i * 8) = o;
}

// ---------------- QKV projection GEMM, lane-ordered LDS ----------------
// 128x128 tile, BK=64, 4 waves 2x2, wave 64x64 = 4x4 16x16x32 MFMA x 2 ks.
// LDS 16B-unit u = frag*64 + lane; frag = half*8 + i*2 + ks holds
// tile[row = half*64 + i*16 + (lane&15)][k = ks*32 + (lane>>4)*8 ..+7].
__global__ __launch_bounds__(256) void qkv_gemm(const unsigned short* __restrict__ A,
                                                const unsigned short* __restrict__ Bw,
                                                const float* __restrict__ bias,
                                                unsigned short* __restrict__ qb,
                                                unsigned short* __restrict__ kvb) {
  const int K = 1024;
  __shared__ unsigned short As[128 * 64];
  __shared__ unsigned short Bs[128 * 64];
  int tid = threadIdx.x;
  int wave = tid >> 6, lane = tid & 63;
  int q4 = lane >> 4, l16 = lane & 15;
  int bm = blockIdx.x, bn = blockIdx.y;

  f32x4 zero = {0.f, 0.f, 0.f, 0.f};
  f32x4 acc[4][4];
#pragma unroll
  for (int i = 0; i < 4; ++i)
#pragma unroll
    for (int j = 0; j < 4; ++j) acc[i][j] = zero;

  const unsigned short* Ab = A + (size_t)(bm * 128) * K;
  const unsigned short* Bb = Bw + (size_t)(bn * 128) * K;

  // staging: inst t4 = wave*4+j covers units u = t4*64 + lane
  const int lanec = (lane & 15) * K + (lane >> 4) * 8;  // per-lane global part
  int ac[4];
  unsigned short *lap[4], *lbp[4];
#pragma unroll
  for (int j = 0; j < 4; ++j) {
    int t4 = wave * 4 + j;
    ac[j] = ((t4 >> 3) * 64 + ((t4 >> 1) & 3) * 16) * K + (t4 & 1) * 32;
    lap[j] = As + t4 * 512;
    lbp[j] = Bs + t4 * 512;
  }

  for (int kt = 0; kt < 16; ++kt) {
    __syncthreads();
    int kbase = kt * 64;
#pragma unroll
    for (int j = 0; j < 4; ++j) {
      async_copy16(Ab + kbase + ac[j] + lanec, lap[j]);
      async_copy16(Bb + kbase + ac[j] + lanec, lbp[j]);
    }
    __syncthreads();
#pragma unroll
    for (int ks = 0; ks < 2; ++ks) {
      short8 af[4], bf[4];
#pragma unroll
      for (int i = 0; i < 4; ++i)
        af[i] = *(const short8*)(&As[((wave & 1) * 8 + i * 2 + ks) * 512 + lane * 8]);
#pragma unroll
      for (int j = 0; j < 4; ++j)
        bf[j] = *(const short8*)(&Bs[((wave >> 1) * 8 + j * 2 + ks) * 512 + lane * 8]);
#pragma unroll
      for (int i = 0; i < 4; ++i)
#pragma unroll
        for (int j = 0; j < 4; ++j)
          acc[i][j] = __builtin_amdgcn_mfma_f32_16x16x32_bf16(af[i], bf[j], acc[i][j], 0, 0, 0);
    }
  }

  // epilogue: +bias; q *0.125*log2e -> qb[bh][t][d]; k,v -> pre-tiled kvb.
  const float QSCALE = 0.18033688011112042f;
  int rowbase = bm * 128 + (wave & 1) * 64;
  int colbase = bn * 128 + (wave >> 1) * 64;
#pragma unroll
  for (int j = 0; j < 4; ++j) {
    int o = colbase + j * 16 + l16;
    float bv = bias[o];
#pragma unroll
    for (int i = 0; i < 4; ++i) {
      int r0 = rowbase + i * 16 + q4 * 4;  // global row (b*2048+t), mult of 4
      int b = r0 >> 11, t0 = r0 & 2047;    // 4 consecutive t share b, st
      if (o < 1024) {
        int h = o >> 6, d = o & 63;
#pragma unroll
        for (int r = 0; r < 4; ++r)
          qb[((((size_t)b * 16 + h) * 2048 + t0 + r) << 6) + d] =
              f2bf((acc[i][j][r] + bv) * QSCALE);
      } else if (o < 2048) {
        int o2 = o - 1024;
        int h = o2 >> 6, dd = o2 & 63;
        int st = t0 >> 6, s6 = t0 & 63;
        int ns = s6 >> 4, l16p = s6 & 15;
        int ks = dd >> 5, q4p = (dd & 31) >> 3, jj = dd & 7;
        size_t base = ((size_t)(b * 16 + h) * 32 + st) * 8192 +
                      ((ns * 2 + ks) * 64 + q4p * 16 + l16p) * 8 + jj;
#pragma unroll
        for (int r = 0; r < 4; ++r)
          kvb[base + r * 8] = f2bf(acc[i][j][r] + bv);
      } else {
        int o3 = o - 2048;
        int h = o3 >> 6, dd = o3 & 63;
        int st = t0 >> 6, sb = (t0 & 63) >> 3, j0 = t0 & 7;
        size_t base = ((size_t)(b * 16 + h) * 32 + st) * 8192 + 4096 +
                      (sb * 64 + dd) * 8 + j0;
        ushort4 pk;
        pk.x = f2bf(acc[i][j][0] + bv);
        pk.y = f2bf(acc[i][j][1] + bv);
        pk.z = f2bf(acc[i][j][2] + bv);
        pk.w = f2bf(acc[i][j][3] + bv);
        *(ushort4*)(&kvb[base]) = pk;
      }
    }
  }
}

// ---------------- Flash attention: wave-private subtiles ----------------
// Grid (16, 64), 256 thr. Block does q-tiles bx and 31-bx (64 t each).
// Wave w processes subtiles st = w, w+4, ... <= qt in its own 16KB LDS region.
// Partial O^T (and l) summed across waves via LDS reduction (fixed-m => additive).
__global__ __launch_bounds__(256, 2) void flash_attn(const unsigned short* __restrict__ qb,
                                                     const unsigned short* __restrict__ kvb,
                                                     float* __restrict__ out) {
  __shared__ __align__(16) unsigned short stage[4][8192];  // 64KB, per-wave 16KB
  __shared__ float lred[4][4][64];                         // [srcwave][mt][lane]

  const int tid = threadIdx.x;
  const int wave = tid >> 6, lane = tid & 63;
  const int q4 = lane >> 4, l16 = lane & 15;
  const int bx = blockIdx.x, bh = blockIdx.y;
  const int b = bh >> 4, h = bh & 15;

  const unsigned short* Qg = qb + (size_t)bh * (2048 * 64);
  const unsigned short* KVg = kvb + (size_t)bh * 32 * 8192;
  unsigned short* mylds = &stage[wave][0];
  const s16x4 ones = {(short)0x3F80, (short)0x3F80, (short)0x3F80, (short)0x3F80};

  for (int pass = 0; pass < 2; ++pass) {
    const int qt = pass ? 31 - bx : bx;

    short8 qf[4][2];
#pragma unroll
    for (int mt = 0; mt < 4; ++mt)
#pragma unroll
      for (int ks = 0; ks < 2; ++ks)
        qf[mt][ks] = *(const short8*)(Qg + (size_t)(qt * 64 + mt * 16 + l16) * 64 +
                                      ks * 32 + q4 * 8);

    f32x4 zero = {0.f, 0.f, 0.f, 0.f};
    f32x4 oT[4][4];  // [mt][nd]
#pragma unroll
    for (int mt = 0; mt < 4; ++mt)
#pragma unroll
      for (int nd = 0; nd < 4; ++nd) oT[mt][nd] = zero;
    f32x4 l_acc[4] = {zero, zero, zero, zero};

    for (int st = wave; st <= qt; st += 4) {
      const unsigned short* tile = KVg + (size_t)st * 8192;
      asm volatile("" ::: "memory");  // keep prior reads before new DMAs
#pragma unroll
      for (int i = 0; i < 16; ++i)
        async_copy16(tile + i * 512 + lane * 8, mylds + i * 512);
      asm volatile("s_waitcnt vmcnt(0)" ::: "memory");

      const bool diag = (st == qt);
#pragma unroll
      for (int ns = 0; ns < 4; ++ns) {
        short8 kf0 = *(const short8*)(mylds + (ns * 2 + 0) * 512 + lane * 8);
        short8 kf1 = *(const short8*)(mylds + (ns * 2 + 1) * 512 + lane * 8);
        f32x4 sT[4];
#pragma unroll
        for (int mt = 0; mt < 4; ++mt) {
          sT[mt] = __builtin_amdgcn_mfma_f32_16x16x32_bf16(kf0, qf[mt][0], zero, 0, 0, 0);
          sT[mt] = __builtin_amdgcn_mfma_f32_16x16x32_bf16(kf1, qf[mt][1], sT[mt], 0, 0, 0);
        }
        if (diag) {
          int sgb = st * 64 + ns * 16 + q4 * 4;
#pragma unroll
          for (int mt = 0; mt < 4; ++mt) {
            int tg = qt * 64 + mt * 16 + l16;
#pragma unroll
            for (int r = 0; r < 4; ++r)
              if (sgb + r > tg) sT[mt][r] = -3.0e38f;
          }
        }
        // fixed-m: P = exp2(s); masked -> 0
        s16x4 pf[4];
#pragma unroll
        for (int mt = 0; mt < 4; ++mt) {
          union { unsigned int u[2]; s16x4 s4; } pu;
          pu.u[0] = pack_bf16(exp2f(sT[mt][0]), exp2f(sT[mt][1]));
          pu.u[1] = pack_bf16(exp2f(sT[mt][2]), exp2f(sT[mt][3]));
          pf[mt] = pu.s4;
        }
#pragma unroll
        for (int nd = 0; nd < 4; ++nd) {
          s16x4 vf = *(const s16x4*)(mylds + 4096 +
                        ((ns * 2 + (q4 >> 1)) * 64 + nd * 16 + l16) * 8 + (q4 & 1) * 4);
#pragma unroll
          for (int mt = 0; mt < 4; ++mt)
            oT[mt][nd] = __builtin_amdgcn_mfma_f32_16x16x16bf16_1k(vf, pf[mt], oT[mt][nd], 0, 0, 0);
        }
#pragma unroll
        for (int mt = 0; mt < 4; ++mt)
          l_acc[mt] = __builtin_amdgcn_mfma_f32_16x16x16bf16_1k(ones, pf[mt], l_acc[mt], 0, 0, 0);
      }
    }

    // ---- cross-wave reduction ----
    f32x4* rw = (f32x4*)&stage[wave][0];  // 1024 f32x4 per wave region
#pragma unroll
    for (int mt = 0; mt < 4; ++mt) {
#pragma unroll
      for (int nd = 0; nd < 4; ++nd) rw[(mt * 4 + nd) * 64 + lane] = oT[mt][nd];
      lred[wave][mt][lane] = l_acc[mt][0];
    }
    __syncthreads();
    f32x4* r4 = (f32x4*)&stage[0][0];
#pragma unroll
    for (int k = 0; k < 4; ++k) {
      int idx = tid + k * 256;
      r4[idx] = r4[idx] + r4[idx + 1024] + r4[idx + 2048] + r4[idx + 3072];
    }
    __syncthreads();

    // wave w writes strip mt = w
    float lt = lred[0][wave][l16] + lred[1][wave][l16] +
               lred[2][wave][l16] + lred[3][wave][l16];
    float inv = 1.0f / lt;
    int t = qt * 64 + wave * 16 + l16;
    float* op = out + (size_t)(b * 2048 + t) * 1024 + h * 64 + q4 * 4;
#pragma unroll
    for (int nd = 0; nd < 4; ++nd) {
      f32x4 v = r4[(wave * 4 + nd) * 64 + lane];
      float4 o4 = {v[0] * inv, v[1] * inv, v[2] * inv, v[3] * inv};
      *(float4*)(op + nd * 16) = o4;
    }
    __syncthreads();  // protect stage reuse in next pass
  }
}

extern "C" void kernel_launch(void* const* d_in, const int* in_sizes, int n_in,
                              void* d_out, int out_size, void* d_ws, size_t ws_size,
                              hipStream_t stream) {
  const float* x = (const float*)d_in[0];
  const float* W = (const float*)d_in[1];
  const float* bias = (const float*)d_in[2];
  float* out = (float*)d_out;

  char* ws = (char*)d_ws;
  unsigned short* xb = (unsigned short*)(ws);
  unsigned short* wb = (unsigned short*)(ws + 16777216);
  unsigned short* qb = (unsigned short*)(ws + 23068672);
  unsigned short* kvb = (unsigned short*)(ws + 39845888);

  hipLaunchKernelGGL(cvt_bf16, dim3(4096), dim3(256), 0, stream, x, xb, 1048576);
  hipLaunchKernelGGL(cvt_bf16, dim3(1536), dim3(256), 0, stream, W, wb, 393216);
  hipLaunchKernelGGL(qkv_gemm, dim3(64, 24), dim3(256), 0, stream, xb, wb, bias,
                     qb, kvb);
  hipLaunchKernelGGL(flash_attn, dim3(16, 64), dim3(256), 0, stream, qb, kvb, out);
}